// Round 17
// baseline (63.877 us; speedup 1.0000x reference)
//
#include <hip/hip_runtime.h>
#include <hip/hip_bf16.h>

#define B_  8
#define S_  2048
#define D_  128
#define H_  4
#define HD_ 32
#define BH_ (B_ * H_)

typedef __bf16 bf16x8 __attribute__((ext_vector_type(8)));
typedef float f32x16 __attribute__((ext_vector_type(16)));

__device__ inline bf16x8 ld8(const __hip_bfloat16* p) {
    return *reinterpret_cast<const bf16x8*>(p);
}
__device__ inline unsigned cvtpk(float lo, float hi) {
    unsigned r;
    asm("v_cvt_pk_bf16_f32 %0, %1, %2" : "=v"(r) : "v"(lo), "v"(hi));
    return r;
}
__device__ inline void swap32(unsigned &a, unsigned &b) {
    asm("v_permlane32_swap_b32 %0, %1" : "+v"(a), "+v"(b));
}
__device__ inline float ex2(float x) { return __builtin_amdgcn_exp2f(x); }

// ---------------------------------------------------------------------------
// QKV GEMM with in-block weight staging (r16 validated) + out-zeroing.
// Block = (mblk, head): 128 m-rows x one head's 96 w-rows. Also zeroes its
// 32 rows of `out` (plain stores) so the fused fattn+proj can atomicAdd.
// ---------------------------------------------------------------------------
__global__ __launch_bounds__(256) void qkv_mfma(const float* __restrict__ x,
                                                const float* __restrict__ wa,
                                                __hip_bfloat16* __restrict__ Qb,
                                                __hip_bfloat16* __restrict__ Kb,
                                                __hip_bfloat16* __restrict__ Vt,
                                                float* __restrict__ out) {
    __shared__ __align__(16) __hip_bfloat16 wl[96][136];

    const int head = blockIdx.x & 3;
    const int mblk = blockIdx.x >> 2;
    const int tid  = threadIdx.x;

    // zero this block's 32 rows of out (4096 floats, coalesced float4)
    {
        float4 z4 = make_float4(0.f, 0.f, 0.f, 0.f);
        float4* zp = reinterpret_cast<float4*>(out + (mblk * 128 + head * 32) * 128);
#pragma unroll
        for (int i = 0; i < 4; ++i) zp[tid + 256 * i] = z4;
    }

    // stage: wl[sec*32+nloc][k] = wa[k][sec*128 + head*32 + nloc]
    for (int idx = tid; idx < 128 * 96; idx += 256) {
        const int k = idx / 96;
        const int c = idx - k * 96;               // c = sec*32 + nloc
        const int sec = c >> 5, nloc = c & 31;
        wl[c][k] = __float2bfloat16(wa[k * 384 + sec * 128 + head * 32 + nloc]);
    }
    __syncthreads();

    const int wave = tid >> 6;                    // m-subtile
    const int lane = tid & 63;
    const int lq   = lane & 31;
    const int hi   = lane >> 5;
    const int m0   = mblk * 128 + wave * 32;

    const float* ax = x + (m0 + lq) * 128 + 8 * hi;
    const __hip_bfloat16* bq = &wl[lq][8 * hi];
    const __hip_bfloat16* bk = &wl[32 + lq][8 * hi];
    const __hip_bfloat16* bv = &wl[64 + lq][8 * hi];

    f32x16 aq = {}, ak = {}, av = {};
#pragma unroll
    for (int ks = 0; ks < 8; ++ks) {
        float4 x0 = *reinterpret_cast<const float4*>(ax + 16 * ks);
        float4 x1 = *reinterpret_cast<const float4*>(ax + 16 * ks + 4);
        union { unsigned u[4]; bf16x8 v; } af;
        af.u[0] = cvtpk(x0.x, x0.y); af.u[1] = cvtpk(x0.z, x0.w);
        af.u[2] = cvtpk(x1.x, x1.y); af.u[3] = cvtpk(x1.z, x1.w);
        const bf16x8 wqf = ld8(bq + 16 * ks);
        const bf16x8 wkf = ld8(bk + 16 * ks);
        const bf16x8 wvf = ld8(bv + 16 * ks);
        // Q/K swapped (lane = m-row) -> contiguous hd per thread on store
        aq = __builtin_amdgcn_mfma_f32_32x32x16_bf16(wqf, af.v, aq, 0, 0, 0);
        ak = __builtin_amdgcn_mfma_f32_32x32x16_bf16(wkf, af.v, ak, 0, 0, 0);
        // V normal (lane = hd) for transposed Vt store
        av = __builtin_amdgcn_mfma_f32_32x32x16_bf16(af.v, wvf, av, 0, 0, 0);
    }

    const int b  = m0 >> 11;
    const int s0 = m0 & (S_ - 1);
    const int bh = b * H_ + head;
    const float qs = 0.2550052557342824f;         // 1/sqrt(32) * log2(e)

    __hip_bfloat16* qrow = Qb + (bh * S_ + s0 + lq) * HD_ + 4 * hi;
    __hip_bfloat16* krow = Kb + (bh * S_ + s0 + lq) * HD_ + 4 * hi;
#pragma unroll
    for (int g = 0; g < 4; ++g) {
        union { __hip_bfloat16 h[4]; ushort4 u; } pq, pk;
#pragma unroll
        for (int j = 0; j < 4; ++j) {
            pq.h[j] = __float2bfloat16(aq[4 * g + j] * qs);
            pk.h[j] = __float2bfloat16(ak[4 * g + j]);
        }
        *reinterpret_cast<ushort4*>(qrow + 8 * g) = pq.u;
        *reinterpret_cast<ushort4*>(krow + 8 * g) = pk.u;
    }
    __hip_bfloat16* vbase = Vt + (bh * HD_ + lq) * S_ + s0;
#pragma unroll
    for (int g = 0; g < 4; ++g) {
        union { __hip_bfloat16 h[4]; ushort4 u; } pv;
#pragma unroll
        for (int j = 0; j < 4; ++j) pv.h[j] = __float2bfloat16(av[4 * g + j]);
        *reinterpret_cast<ushort4*>(vbase + 8 * g + 4 * hi) = pv.u;
    }
}

// ---------------------------------------------------------------------------
// Fused flash attention + projection partial. 64-q blocks (r14/r16 attention
// body byte-preserved). After the online-softmax combine, O (bf16) goes to
// LDS and the block computes its head's k-slice of out = AO @ w_proj:
//   partial(64x128) = O_h(64x32) @ W[h*32:(h+1)*32, :]  -> atomicAdd to out.
// No inter-block dependency; out pre-zeroed by qkv dispatch.
// ---------------------------------------------------------------------------
__global__ __launch_bounds__(256, 4) void fattn_kernel(
    const __hip_bfloat16* __restrict__ Qb,
    const __hip_bfloat16* __restrict__ Kb,
    const __hip_bfloat16* __restrict__ Vt,
    const float* __restrict__ wp,
    float* __restrict__ out)
{
    __shared__ float Ol[4][64][33];
    __shared__ float Ll[4][64];
    __shared__ __align__(16) __hip_bfloat16 Osm[64][40];
    __shared__ __align__(16) __hip_bfloat16 wpl[128][40];

    const int bh   = blockIdx.x & 31;             // head -> stable XCD
    const int qt2  = 31 - (blockIdx.x >> 5);      // 0..31, longest first
    const int tid  = threadIdx.x;
    const int wv   = tid >> 6;
    const int lane = tid & 63;
    const int lq   = lane & 31;
    const int hi   = lane >> 5;
    const int h    = bh & 3;

    // stage this head's w_proj slice: wpl[n][k] = wp[(h*32+k)*128 + n]
    for (int idx = tid; idx < 128 * 32; idx += 256) {
        const int k = idx >> 7, n = idx & 127;    // consecutive tid -> n consec
        wpl[n][k] = __float2bfloat16(wp[(h * 32 + k) * 128 + n]);
    }

    const int q0  = qt2 * 64;
    const int qtA = 2 * qt2;
    const int qtB = qtA + 1;
    const int nt  = qtB + 1;

    const __hip_bfloat16* qrowA = Qb + (bh * S_ + q0 + lq) * HD_ + 8 * hi;
    const __hip_bfloat16* qrowB = qrowA + 32 * HD_;
    const bf16x8 qfA0 = ld8(qrowA), qfA1 = ld8(qrowA + 16);
    const bf16x8 qfB0 = ld8(qrowB), qfB1 = ld8(qrowB + 16);

    const __hip_bfloat16* kp = Kb + bh * S_ * HD_ + lq * HD_ + 8 * hi;
    const __hip_bfloat16* vp = Vt + (bh * HD_ + lq) * S_ + 8 * hi;

    f32x16 oaccA = {}, oaccB = {};
    float lsumA = 0.f, lsumB = 0.f;

    bf16x8 k0a = {}, k1a = {}, v0a = {}, v1a = {};
    if (wv < nt) {
        k0a = ld8(kp + wv * 32 * HD_); k1a = ld8(kp + wv * 32 * HD_ + 16);
        v0a = ld8(vp + wv * 32);       v1a = ld8(vp + wv * 32 + 16);
    }

    for (int t = wv; t < nt; t += 4) {
        const bf16x8 ck0 = k0a, ck1 = k1a, cv0 = v0a, cv1 = v1a;
        if (t + 4 < nt) {
            const __hip_bfloat16* kn = kp + (t + 4) * 32 * HD_;
            const __hip_bfloat16* vn = vp + (t + 4) * 32;
            k0a = ld8(kn); k1a = ld8(kn + 16);
            v0a = ld8(vn); v1a = ld8(vn + 16);
        }

        if (t <= qtA) {
            __builtin_amdgcn_s_setprio(1);
            f32x16 s = {};
            s = __builtin_amdgcn_mfma_f32_32x32x16_bf16(ck0, qfA0, s, 0, 0, 0);
            s = __builtin_amdgcn_mfma_f32_32x32x16_bf16(ck1, qfA1, s, 0, 0, 0);
            __builtin_amdgcn_s_setprio(0);

            if (t == qtA) {
#pragma unroll
                for (int r = 0; r < 16; ++r) {
                    const int kloc = (r & 3) + 8 * (r >> 2) + 4 * hi;
                    s[r] = (kloc > lq) ? -1e30f : s[r];
                }
            }
#pragma unroll
            for (int r = 0; r < 16; ++r) s[r] = ex2(s[r]);
            {
                float p0 = (s[0] + s[1]) + (s[2] + s[3]);
                float p1 = (s[4] + s[5]) + (s[6] + s[7]);
                float p2 = (s[8] + s[9]) + (s[10] + s[11]);
                float p3 = (s[12] + s[13]) + (s[14] + s[15]);
                lsumA += (p0 + p1) + (p2 + p3);
            }
            unsigned a0 = cvtpk(s[0], s[1]),   a1 = cvtpk(s[2], s[3]);
            unsigned a2 = cvtpk(s[4], s[5]),   a3 = cvtpk(s[6], s[7]);
            swap32(a0, a2); swap32(a1, a3);
            unsigned b0 = cvtpk(s[8], s[9]),   b1 = cvtpk(s[10], s[11]);
            unsigned b2 = cvtpk(s[12], s[13]), b3 = cvtpk(s[14], s[15]);
            swap32(b0, b2); swap32(b1, b3);
            union { unsigned u[4]; bf16x8 v; } pb0, pb1;
            pb0.u[0] = a0; pb0.u[1] = a1; pb0.u[2] = a2; pb0.u[3] = a3;
            pb1.u[0] = b0; pb1.u[1] = b1; pb1.u[2] = b2; pb1.u[3] = b3;

            __builtin_amdgcn_s_setprio(1);
            oaccA = __builtin_amdgcn_mfma_f32_32x32x16_bf16(cv0, pb0.v, oaccA, 0, 0, 0);
            oaccA = __builtin_amdgcn_mfma_f32_32x32x16_bf16(cv1, pb1.v, oaccA, 0, 0, 0);
            __builtin_amdgcn_s_setprio(0);
        }

        {
            __builtin_amdgcn_s_setprio(1);
            f32x16 s = {};
            s = __builtin_amdgcn_mfma_f32_32x32x16_bf16(ck0, qfB0, s, 0, 0, 0);
            s = __builtin_amdgcn_mfma_f32_32x32x16_bf16(ck1, qfB1, s, 0, 0, 0);
            __builtin_amdgcn_s_setprio(0);

            if (t == qtB) {
#pragma unroll
                for (int r = 0; r < 16; ++r) {
                    const int kloc = (r & 3) + 8 * (r >> 2) + 4 * hi;
                    s[r] = (kloc > lq) ? -1e30f : s[r];
                }
            }
#pragma unroll
            for (int r = 0; r < 16; ++r) s[r] = ex2(s[r]);
            {
                float p0 = (s[0] + s[1]) + (s[2] + s[3]);
                float p1 = (s[4] + s[5]) + (s[6] + s[7]);
                float p2 = (s[8] + s[9]) + (s[10] + s[11]);
                float p3 = (s[12] + s[13]) + (s[14] + s[15]);
                lsumB += (p0 + p1) + (p2 + p3);
            }
            unsigned a0 = cvtpk(s[0], s[1]),   a1 = cvtpk(s[2], s[3]);
            unsigned a2 = cvtpk(s[4], s[5]),   a3 = cvtpk(s[6], s[7]);
            swap32(a0, a2); swap32(a1, a3);
            unsigned b0 = cvtpk(s[8], s[9]),   b1 = cvtpk(s[10], s[11]);
            unsigned b2 = cvtpk(s[12], s[13]), b3 = cvtpk(s[14], s[15]);
            swap32(b0, b2); swap32(b1, b3);
            union { unsigned u[4]; bf16x8 v; } pb0, pb1;
            pb0.u[0] = a0; pb0.u[1] = a1; pb0.u[2] = a2; pb0.u[3] = a3;
            pb1.u[0] = b0; pb1.u[1] = b1; pb1.u[2] = b2; pb1.u[3] = b3;

            __builtin_amdgcn_s_setprio(1);
            oaccB = __builtin_amdgcn_mfma_f32_32x32x16_bf16(cv0, pb0.v, oaccB, 0, 0, 0);
            oaccB = __builtin_amdgcn_mfma_f32_32x32x16_bf16(cv1, pb1.v, oaccB, 0, 0, 0);
            __builtin_amdgcn_s_setprio(0);
        }
    }

    lsumA += __shfl_xor(lsumA, 32);
    lsumB += __shfl_xor(lsumB, 32);

#pragma unroll
    for (int r = 0; r < 16; ++r) {
        const int d = (r & 3) + 8 * (r >> 2) + 4 * hi;
        Ol[wv][lq][d]      = oaccA[r];
        Ol[wv][32 + lq][d] = oaccB[r];
    }
    if (hi == 0) { Ll[wv][lq] = lsumA; Ll[wv][32 + lq] = lsumB; }
    __syncthreads();

    // combine 4 partials -> normalized bf16 O in LDS (Osm)
    {
        const int q  = tid >> 2;                  // 0..63
        const int d0 = (tid & 3) * 8;             // 0,8,16,24
        const float lst = Ll[0][q] + Ll[1][q] + Ll[2][q] + Ll[3][q];
        const float inv = 1.f / lst;
#pragma unroll
        for (int g = 0; g < 2; ++g) {
            union { __hip_bfloat16 h4[4]; ushort4 u; } st;
#pragma unroll
            for (int j = 0; j < 4; ++j) {
                const int d = d0 + 4 * g + j;
                const float o = Ol[0][q][d] + Ol[1][q][d] + Ol[2][q][d] + Ol[3][q][d];
                st.h4[j] = __float2bfloat16(o * inv);
            }
            *reinterpret_cast<ushort4*>(&Osm[q][d0 + 4 * g]) = st.u;
        }
    }
    __syncthreads();

    // projection partial: out[q0..q0+63][:] += O_h(64x32) @ W_h(32x128).
    // Wave wv owns n-range wv*32; both m-tiles reuse the same W-frags.
    {
        const int b = bh >> 2;
        const bf16x8 wf0 = ld8(&wpl[wv * 32 + lq][8 * hi]);        // k=8hi+e
        const bf16x8 wf1 = ld8(&wpl[wv * 32 + lq][16 + 8 * hi]);   // k=16+8hi+e
#pragma unroll
        for (int mt = 0; mt < 2; ++mt) {
            const bf16x8 of0 = ld8(&Osm[mt * 32 + lq][8 * hi]);
            const bf16x8 of1 = ld8(&Osm[mt * 32 + lq][16 + 8 * hi]);
            f32x16 acc = {};
            acc = __builtin_amdgcn_mfma_f32_32x32x16_bf16(of0, wf0, acc, 0, 0, 0);
            acc = __builtin_amdgcn_mfma_f32_32x32x16_bf16(of1, wf1, acc, 0, 0, 0);
            float* obase = out + (b * S_ + q0 + mt * 32) * 128 + wv * 32 + lq;
#pragma unroll
            for (int r = 0; r < 16; ++r) {
                const int row = (r & 3) + 8 * (r >> 2) + 4 * hi;
                atomicAdd(obase + row * 128, acc[r]);
            }
        }
    }
}

// ---------------------------------------------------------------------------
extern "C" void kernel_launch(void* const* d_in, const int* in_sizes, int n_in,
                              void* d_out, int out_size, void* d_ws, size_t ws_size,
                              hipStream_t stream) {
    const float* x      = (const float*)d_in[0];
    const float* w_attn = (const float*)d_in[1];
    const float* w_proj = (const float*)d_in[2];
    float* out = (float*)d_out;

    char* ws = (char*)d_ws;
    __hip_bfloat16* Qb = (__hip_bfloat16*)(ws);                     // 4 MB
    __hip_bfloat16* Kb = (__hip_bfloat16*)(ws + (4 << 20));         // 4 MB
    __hip_bfloat16* Vt = (__hip_bfloat16*)(ws + (8 << 20));         // 4 MB

    qkv_mfma<<<512, 256, 0, stream>>>(x, w_attn, Qb, Kb, Vt, out);
    fattn_kernel<<<BH_ * 32, 256, 0, stream>>>(Qb, Kb, Vt, w_proj, out);
}